// Round 2
// baseline (1268.085 us; speedup 1.0000x reference)
//
#include <hip/hip_runtime.h>
#include <cmath>
#include <complex>

#define BT 16   // batch tile per block
#define NP 11   // number of tensor-product paths

// ---- path metadata (compile-time) ----------------------------------------
// paths in reference order: (i1,i2,io) =
// (0,0,0),(0,1,1),(0,2,2),(1,0,1),(1,1,0),(1,1,2),(1,2,1),(2,0,2),(2,1,1),(2,2,0),(2,2,2)
constexpr int P_N1[NP]   = {1,1,1, 3,3,3,3, 5,5,5,5};              // 2*l1+1
constexpr int P_N2[NP]   = {1,3,5, 1,3,3,5, 1,3,5,5};              // 2*l2+1
constexpr int P_NO[NP]   = {1,3,5, 3,1,5,3, 5,3,1,5};              // 2*lo+1
constexpr int P_S1[NP]   = {0,0,0, 128,128,128,128, 512,512,512,512}; // x1 offset
constexpr int P_S2[NP]   = {0,1,4, 0,1,1,4, 0,1,4,4};              // x2 offset
constexpr int P_KO[NP]   = {0,1,4, 1,0,4,1, 4,1,0,4};              // acc k-slot base (io: 0->0,1->1,2->4)
constexpr int P_MOFF[NP] = {0,1,4,9,18,21,36,45,70,85,90};         // M LDS offsets (sizes no*n1, total 115)
constexpr int P_W3J[NP]  = {0,1,10,35,44,53,98,143,168,213,238};   // w3j offsets (sizes n1*n2*no, total 363)

struct TPConst {
    float w3j[363];
    float sqa[11];
};

// ---- host-side exact mirror of the reference w3j computation -------------
namespace {

double hfact(int n) { double r = 1.0; for (int i = 2; i <= n; ++i) r *= (double)i; return r; }

void hsu2cg(int j1, int j2, int j3, double* C) {
    const int d2 = 2*j2+1, d3 = 2*j3+1, d1 = 2*j1+1;
    for (int i = 0; i < d1*d2*d3; ++i) C[i] = 0.0;
    for (int m1 = -j1; m1 <= j1; ++m1)
        for (int m2 = -j2; m2 <= j2; ++m2) {
            const int m3 = m1 + m2;
            if (m3 < -j3 || m3 > j3) continue;
            double pref = std::sqrt((2*j3+1) * hfact(j3+j1-j2) * hfact(j3-j1+j2) * hfact(j1+j2-j3) / hfact(j1+j2+j3+1));
            pref *= std::sqrt(hfact(j3+m3)*hfact(j3-m3)*hfact(j1-m1)*hfact(j1+m1)*hfact(j2-m2)*hfact(j2+m2));
            double s = 0.0;
            for (int k = 0; k <= j1+j2-j3; ++k) {
                if (j1-m1-k < 0 || j2+m2-k < 0 || j3-j2+m1+k < 0 || j3-j1-m2+k < 0) continue;
                double d = hfact(k)*hfact(j1+j2-j3-k)*hfact(j1-m1-k)*hfact(j2+m2-k)*hfact(j3-j2+m1+k)*hfact(j3-j1-m2+k);
                s += ((k & 1) ? -1.0 : 1.0) / d;
            }
            C[((j1+m1)*d2 + (j2+m2))*d3 + (j3+m3)] = pref * s;
        }
}

void hrealbasis(int l, std::complex<double>* q) {  // (2l+1)x(2l+1), row-major
    const int d = 2*l+1;
    for (int i = 0; i < d*d; ++i) q[i] = 0.0;
    const double is2 = 1.0 / std::sqrt(2.0);
    for (int m = -l; m < 0; ++m) {
        q[(l+m)*d + (l - m)] = is2;                                  // l+|m| = l-m for m<0
        q[(l+m)*d + (l + m)] = std::complex<double>(0.0, -is2);      // l-|m| = l+m
    }
    q[l*d + l] = 1.0;
    for (int m = 1; m <= l; ++m) {
        const double sgn = (m & 1) ? -1.0 : 1.0;
        q[(l+m)*d + (l + m)] = sgn * is2;
        q[(l+m)*d + (l - m)] = std::complex<double>(0.0, sgn * is2);
    }
    std::complex<double> ph(1.0, 0.0);
    const std::complex<double> mi(0.0, -1.0);
    for (int i = 0; i < l; ++i) ph *= mi;   // (-i)^l
    for (int i = 0; i < d*d; ++i) q[i] *= ph;
}

void hw3j(int l1, int l2, int l3, float* out) {
    const int d1 = 2*l1+1, d2 = 2*l2+1, d3 = 2*l3+1;
    double C[125];
    hsu2cg(l1, l2, l3, C);
    std::complex<double> Q1[25], Q2[25], Q3[25];
    hrealbasis(l1, Q1); hrealbasis(l2, Q2); hrealbasis(l3, Q3);
    double R[125]; double norm2 = 0.0;
    for (int j = 0; j < d1; ++j)
        for (int l = 0; l < d2; ++l)
            for (int m = 0; m < d3; ++m) {
                std::complex<double> s(0.0, 0.0);
                for (int i = 0; i < d1; ++i)
                    for (int k = 0; k < d2; ++k)
                        for (int n = 0; n < d3; ++n)
                            s += Q1[i*d1 + j] * Q2[k*d2 + l] * std::conj(Q3[n*d3 + m]) * C[(i*d2 + k)*d3 + n];
                R[(j*d2 + l)*d3 + m] = s.real();
                norm2 += s.real() * s.real();
            }
    const double inv = 1.0 / std::sqrt(norm2);
    for (int i = 0; i < d1*d2*d3; ++i) out[i] = (float)(R[i] * inv);
}

void fill_const(TPConst& tc) {
    const int L1[NP] = {0,0,0,1,1,1,1,2,2,2,2};
    const int L2[NP] = {0,1,2,0,1,1,2,0,1,2,2};
    const int LO[NP] = {0,1,2,1,0,2,1,2,1,0,2};
    const double den[3] = {384.0, 512.0, 512.0};   // path_normalization='element'
    for (int p = 0; p < NP; ++p) {
        hw3j(L1[p], L2[p], LO[p], tc.w3j + P_W3J[p]);
        tc.sqa[p] = (float)std::sqrt((2.0*LO[p] + 1.0) / den[LO[p]]);
    }
}

}  // namespace

// ---- device kernel --------------------------------------------------------
// Phase C thread mapping: b = t>>4 (one batch per thread), w-block = (t&15)*8
// (8 consecutive outputs per thread). ylds layout per path: [b][k][u] with
// per-b stride S = no*128 + 4 floats; the +4 pad puts the 4 distinct b-slices
// read by one wave on distinct bank quads (S mod 32 == 4), and each (b,k,u0)
// row chunk is a 16B-aligned ds_read_b128 broadcast to 16 lanes.
//
// NOTE on launch bounds: occupancy is LDS-capped at 3 blocks/CU (48640 B of
// 160 KiB) — VGPRs are NOT the limiter. Round-1's __launch_bounds__(256,3)
// made the allocator cap at 84 VGPRs (needs ~120 live in phase C) and spilled
// ~70 floats/thread to scratch: WRITE_SIZE 147->292 MB, FETCH +200 MB.
// Plain (256) lets the allocator use what it needs; do not re-add a min-
// occupancy argument here.
__global__ __launch_bounds__(256)
void tp_kernel(const float* __restrict__ x1, const float* __restrict__ x2,
               const float* __restrict__ wsg, float* __restrict__ out, TPConst tc)
{
    __shared__ float Mlds[BT][116];   // per-b M matrices (scaled by sqrt(alpha)), 115 used
    __shared__ float ylds[BT * 644];  // per-path y, layout [b][k][u] stride no*128+4 (max 644)

    const int t = threadIdx.x;
    const long b0 = (long)blockIdx.x * BT;

    // Phase A: M_p[b][k][i] = sum_j C_p[i][j][k] * x2[b][s2+j], scaled
    if (t < BT) {
        float x2v[9];
        #pragma unroll
        for (int j = 0; j < 9; ++j) x2v[j] = x2[(b0 + t)*9 + j];
        #pragma unroll
        for (int p = 0; p < NP; ++p) {
            const int n1 = P_N1[p], n2 = P_N2[p], no = P_NO[p];
            const float sqa = tc.sqa[p];
            #pragma unroll
            for (int k = 0; k < no; ++k)
                #pragma unroll
                for (int i = 0; i < n1; ++i) {
                    float m = 0.f;
                    #pragma unroll
                    for (int j = 0; j < n2; ++j)
                        m += tc.w3j[P_W3J[p] + (i*n2 + j)*no + k] * x2v[P_S2[p] + j];
                    Mlds[t][P_MOFF[p] + k*n1 + i] = m * sqa;
                }
        }
    }

    float acc[8][9];
    #pragma unroll
    for (int wi = 0; wi < 8; ++wi)
        #pragma unroll
        for (int k = 0; k < 9; ++k) acc[wi][k] = 0.f;

    const int uy = t & 127, g = t >> 7;    // phase B: u lane + b group
    const int cb = t >> 4, tw = t & 15;    // phase C: batch + w-octet

    __syncthreads();

    #pragma unroll
    for (int p = 0; p < NP; ++p) {
        const int n1 = P_N1[p], no = P_NO[p];
        const int S = no*128 + 4;          // per-b ylds stride (floats)

        // Phase B: y[b][k][u] = sum_i M[b][k][i] * x1[b, s1 + u*n1 + i]
        #pragma unroll
        for (int bb = 0; bb < 8; ++bb) {
            const int b = g*8 + bb;
            const float* xp = x1 + (b0 + b)*1152 + P_S1[p] + uy*n1;
            float xv[5];
            #pragma unroll
            for (int i = 0; i < n1; ++i) xv[i] = xp[i];
            #pragma unroll
            for (int k = 0; k < no; ++k) {
                float yv = 0.f;
                #pragma unroll
                for (int i = 0; i < n1; ++i) yv += Mlds[b][P_MOFF[p] + k*n1 + i] * xv[i];
                ylds[b*S + k*128 + uy] = yv;
            }
        }
        __syncthreads();

        // Phase C: acc[c][ko+k] += W_p[u][tw*8+c] * y[cb][k][u]
        {
            const int ko = P_KO[p];
            const float* yb = ylds + cb*S;
            const float* wp = wsg + p*16384 + tw*8;
            #pragma unroll 2
            for (int u0 = 0; u0 < 128; u0 += 4) {
                float4 yv4[5];
                #pragma unroll
                for (int k = 0; k < no; ++k)
                    yv4[k] = *(const float4*)(yb + k*128 + u0);
                #pragma unroll
                for (int j = 0; j < 4; ++j) {
                    const float4 wa = *(const float4*)(wp + (u0 + j)*128);
                    const float4 wb = *(const float4*)(wp + (u0 + j)*128 + 4);
                    #pragma unroll
                    for (int k = 0; k < no; ++k) {
                        const float y = (j == 0) ? yv4[k].x
                                      : (j == 1) ? yv4[k].y
                                      : (j == 2) ? yv4[k].z
                                                 : yv4[k].w;
                        acc[0][ko+k] += wa.x * y;
                        acc[1][ko+k] += wa.y * y;
                        acc[2][ko+k] += wa.z * y;
                        acc[3][ko+k] += wa.w * y;
                        acc[4][ko+k] += wb.x * y;
                        acc[5][ko+k] += wb.y * y;
                        acc[6][ko+k] += wb.z * y;
                        acc[7][ko+k] += wb.w * y;
                    }
                }
            }
        }
        __syncthreads();
    }

    // Epilogue: out[b, so + w*(2lo+1) + k], w = tw*8 + c, all float4 stores
    {
        float* op = out + (b0 + cb)*1152;
        // io=0: 8 consecutive w at offset tw*8
        *(float4*)(op + tw*8)     = make_float4(acc[0][0], acc[1][0], acc[2][0], acc[3][0]);
        *(float4*)(op + tw*8 + 4) = make_float4(acc[4][0], acc[5][0], acc[6][0], acc[7][0]);
        // io=1: 24 consecutive floats at 128 + tw*24  (layout w*3+k)
        {
            float b1[24];
            #pragma unroll
            for (int c = 0; c < 8; ++c)
                #pragma unroll
                for (int k = 0; k < 3; ++k) b1[c*3 + k] = acc[c][1 + k];
            #pragma unroll
            for (int q = 0; q < 6; ++q)
                *(float4*)(op + 128 + tw*24 + q*4) = *(const float4*)(b1 + q*4);
        }
        // io=2: 40 consecutive floats at 512 + tw*40  (layout w*5+k)
        {
            float b2[40];
            #pragma unroll
            for (int c = 0; c < 8; ++c)
                #pragma unroll
                for (int k = 0; k < 5; ++k) b2[c*5 + k] = acc[c][4 + k];
            #pragma unroll
            for (int q = 0; q < 10; ++q)
                *(float4*)(op + 512 + tw*40 + q*4) = *(const float4*)(b2 + q*4);
        }
    }
}

// ---- launch ---------------------------------------------------------------
extern "C" void kernel_launch(void* const* d_in, const int* in_sizes, int n_in,
                              void* d_out, int out_size, void* d_ws, size_t ws_size,
                              hipStream_t stream) {
    const float* x1  = (const float*)d_in[0];
    const float* x2  = (const float*)d_in[1];
    const float* wsg = (const float*)d_in[2];
    float* out = (float*)d_out;
    const int B = in_sizes[0] / 1152;   // 32768

    TPConst tc;
    fill_const(tc);   // deterministic; identical on every call (graph-capture safe)

    dim3 grid(B / BT), block(256);
    hipLaunchKernelGGL(tp_kernel, grid, block, 0, stream, x1, x2, wsg, out, tc);
}

// Round 3
// 974.070 us; speedup vs baseline: 1.3018x; 1.3018x over previous
//
#include <hip/hip_runtime.h>
#include <cmath>
#include <complex>

#define BT 16   // batch tile per block
#define NP 11   // number of tensor-product paths

// ---- path metadata (compile-time) ----------------------------------------
// paths in reference order: (i1,i2,io) =
// (0,0,0),(0,1,1),(0,2,2),(1,0,1),(1,1,0),(1,1,2),(1,2,1),(2,0,2),(2,1,1),(2,2,0),(2,2,2)
constexpr int P_N1[NP]   = {1,1,1, 3,3,3,3, 5,5,5,5};              // 2*l1+1
constexpr int P_N2[NP]   = {1,3,5, 1,3,3,5, 1,3,5,5};              // 2*l2+1
constexpr int P_NO[NP]   = {1,3,5, 3,1,5,3, 5,3,1,5};              // 2*lo+1
constexpr int P_S1[NP]   = {0,0,0, 128,128,128,128, 512,512,512,512}; // x1 offset
constexpr int P_S2[NP]   = {0,1,4, 0,1,1,4, 0,1,4,4};              // x2 offset
constexpr int P_KO[NP]   = {0,1,4, 1,0,4,1, 4,1,0,4};              // acc k-slot base (io: 0->0,1->1,2->4)
constexpr int P_MOFF[NP] = {0,1,4,9,18,21,36,45,70,85,90};         // M LDS offsets (sizes no*n1, total 115)
constexpr int P_W3J[NP]  = {0,1,10,35,44,53,98,143,168,213,238};   // w3j offsets (sizes n1*n2*no, total 363)

struct TPConst {
    float w3j[363];
    float sqa[11];
};

// ---- host-side exact mirror of the reference w3j computation -------------
namespace {

double hfact(int n) { double r = 1.0; for (int i = 2; i <= n; ++i) r *= (double)i; return r; }

void hsu2cg(int j1, int j2, int j3, double* C) {
    const int d2 = 2*j2+1, d3 = 2*j3+1, d1 = 2*j1+1;
    for (int i = 0; i < d1*d2*d3; ++i) C[i] = 0.0;
    for (int m1 = -j1; m1 <= j1; ++m1)
        for (int m2 = -j2; m2 <= j2; ++m2) {
            const int m3 = m1 + m2;
            if (m3 < -j3 || m3 > j3) continue;
            double pref = std::sqrt((2*j3+1) * hfact(j3+j1-j2) * hfact(j3-j1+j2) * hfact(j1+j2-j3) / hfact(j1+j2+j3+1));
            pref *= std::sqrt(hfact(j3+m3)*hfact(j3-m3)*hfact(j1-m1)*hfact(j1+m1)*hfact(j2-m2)*hfact(j2+m2));
            double s = 0.0;
            for (int k = 0; k <= j1+j2-j3; ++k) {
                if (j1-m1-k < 0 || j2+m2-k < 0 || j3-j2+m1+k < 0 || j3-j1-m2+k < 0) continue;
                double d = hfact(k)*hfact(j1+j2-j3-k)*hfact(j1-m1-k)*hfact(j2+m2-k)*hfact(j3-j2+m1+k)*hfact(j3-j1-m2+k);
                s += ((k & 1) ? -1.0 : 1.0) / d;
            }
            C[((j1+m1)*d2 + (j2+m2))*d3 + (j3+m3)] = pref * s;
        }
}

void hrealbasis(int l, std::complex<double>* q) {  // (2l+1)x(2l+1), row-major
    const int d = 2*l+1;
    for (int i = 0; i < d*d; ++i) q[i] = 0.0;
    const double is2 = 1.0 / std::sqrt(2.0);
    for (int m = -l; m < 0; ++m) {
        q[(l+m)*d + (l - m)] = is2;                                  // l+|m| = l-m for m<0
        q[(l+m)*d + (l + m)] = std::complex<double>(0.0, -is2);      // l-|m| = l+m
    }
    q[l*d + l] = 1.0;
    for (int m = 1; m <= l; ++m) {
        const double sgn = (m & 1) ? -1.0 : 1.0;
        q[(l+m)*d + (l + m)] = sgn * is2;
        q[(l+m)*d + (l - m)] = std::complex<double>(0.0, sgn * is2);
    }
    std::complex<double> ph(1.0, 0.0);
    const std::complex<double> mi(0.0, -1.0);
    for (int i = 0; i < l; ++i) ph *= mi;   // (-i)^l
    for (int i = 0; i < d*d; ++i) q[i] *= ph;
}

void hw3j(int l1, int l2, int l3, float* out) {
    const int d1 = 2*l1+1, d2 = 2*l2+1, d3 = 2*l3+1;
    double C[125];
    hsu2cg(l1, l2, l3, C);
    std::complex<double> Q1[25], Q2[25], Q3[25];
    hrealbasis(l1, Q1); hrealbasis(l2, Q2); hrealbasis(l3, Q3);
    double R[125]; double norm2 = 0.0;
    for (int j = 0; j < d1; ++j)
        for (int l = 0; l < d2; ++l)
            for (int m = 0; m < d3; ++m) {
                std::complex<double> s(0.0, 0.0);
                for (int i = 0; i < d1; ++i)
                    for (int k = 0; k < d2; ++k)
                        for (int n = 0; n < d3; ++n)
                            s += Q1[i*d1 + j] * Q2[k*d2 + l] * std::conj(Q3[n*d3 + m]) * C[(i*d2 + k)*d3 + n];
                R[(j*d2 + l)*d3 + m] = s.real();
                norm2 += s.real() * s.real();
            }
    const double inv = 1.0 / std::sqrt(norm2);
    for (int i = 0; i < d1*d2*d3; ++i) out[i] = (float)(R[i] * inv);
}

void fill_const(TPConst& tc) {
    const int L1[NP] = {0,0,0,1,1,1,1,2,2,2,2};
    const int L2[NP] = {0,1,2,0,1,1,2,0,1,2,2};
    const int LO[NP] = {0,1,2,1,0,2,1,2,1,0,2};
    const double den[3] = {384.0, 512.0, 512.0};   // path_normalization='element'
    for (int p = 0; p < NP; ++p) {
        hw3j(L1[p], L2[p], LO[p], tc.w3j + P_W3J[p]);
        tc.sqa[p] = (float)std::sqrt((2.0*LO[p] + 1.0) / den[LO[p]]);
    }
}

}  // namespace

// ---- device kernel --------------------------------------------------------
// Phase C thread mapping: b = t>>4 (one batch per thread), w-block = (t&15)*8
// (8 consecutive outputs per thread). ylds layout per path: [b][k][u] with
// per-b stride S = no*128 + 4 floats; the +4 pad puts the 4 distinct b-slices
// read by one wave on distinct bank quads (S mod 32 == 4), and each (b,k,u0)
// row chunk is a 16B-aligned ds_read_b128 broadcast to 16 lanes.
//
// VGPR calibration (measured across rounds on this kernel):
//   (256,3)      -> cap 84  (= 256/3, granule 4): phase C needs ~120 live ->
//                   ~70 f/thread spilled, WRITE_SIZE 147->292 MB.  BAD.
//   (256) plain  -> compiler picks 132: crosses the 128 HW allocation
//                   boundary, resident waves halve (Occupancy 33%->12%),
//                   dur 990->1174 us.  BAD.
//   (256,2)      -> cap 128 (= 256/2): fits phase C live set (~115-125),
//                   stays on the 4-waves/SIMD side of the boundary.
// Occupancy is then LDS-capped at 3 blocks/CU (48640 B of 160 KiB).
__global__ __launch_bounds__(256, 2)
void tp_kernel(const float* __restrict__ x1, const float* __restrict__ x2,
               const float* __restrict__ wsg, float* __restrict__ out, TPConst tc)
{
    __shared__ float Mlds[BT][116];   // per-b M matrices (scaled by sqrt(alpha)), 115 used
    __shared__ float ylds[BT * 644];  // per-path y, layout [b][k][u] stride no*128+4 (max 644)

    const int t = threadIdx.x;
    const long b0 = (long)blockIdx.x * BT;

    // Phase A: M_p[b][k][i] = sum_j C_p[i][j][k] * x2[b][s2+j], scaled
    if (t < BT) {
        float x2v[9];
        #pragma unroll
        for (int j = 0; j < 9; ++j) x2v[j] = x2[(b0 + t)*9 + j];
        #pragma unroll
        for (int p = 0; p < NP; ++p) {
            const int n1 = P_N1[p], n2 = P_N2[p], no = P_NO[p];
            const float sqa = tc.sqa[p];
            #pragma unroll
            for (int k = 0; k < no; ++k)
                #pragma unroll
                for (int i = 0; i < n1; ++i) {
                    float m = 0.f;
                    #pragma unroll
                    for (int j = 0; j < n2; ++j)
                        m += tc.w3j[P_W3J[p] + (i*n2 + j)*no + k] * x2v[P_S2[p] + j];
                    Mlds[t][P_MOFF[p] + k*n1 + i] = m * sqa;
                }
        }
    }

    float acc[8][9];
    #pragma unroll
    for (int wi = 0; wi < 8; ++wi)
        #pragma unroll
        for (int k = 0; k < 9; ++k) acc[wi][k] = 0.f;

    const int uy = t & 127, g = t >> 7;    // phase B: u lane + b group
    const int cb = t >> 4, tw = t & 15;    // phase C: batch + w-octet

    __syncthreads();

    #pragma unroll
    for (int p = 0; p < NP; ++p) {
        const int n1 = P_N1[p], no = P_NO[p];
        const int S = no*128 + 4;          // per-b ylds stride (floats)

        // Phase B: y[b][k][u] = sum_i M[b][k][i] * x1[b, s1 + u*n1 + i]
        #pragma unroll
        for (int bb = 0; bb < 8; ++bb) {
            const int b = g*8 + bb;
            const float* xp = x1 + (b0 + b)*1152 + P_S1[p] + uy*n1;
            float xv[5];
            #pragma unroll
            for (int i = 0; i < n1; ++i) xv[i] = xp[i];
            #pragma unroll
            for (int k = 0; k < no; ++k) {
                float yv = 0.f;
                #pragma unroll
                for (int i = 0; i < n1; ++i) yv += Mlds[b][P_MOFF[p] + k*n1 + i] * xv[i];
                ylds[b*S + k*128 + uy] = yv;
            }
        }
        __syncthreads();

        // Phase C: acc[c][ko+k] += W_p[u][tw*8+c] * y[cb][k][u]
        {
            const int ko = P_KO[p];
            const float* yb = ylds + cb*S;
            const float* wp = wsg + p*16384 + tw*8;
            #pragma unroll 2
            for (int u0 = 0; u0 < 128; u0 += 4) {
                float4 yv4[5];
                #pragma unroll
                for (int k = 0; k < no; ++k)
                    yv4[k] = *(const float4*)(yb + k*128 + u0);
                #pragma unroll
                for (int j = 0; j < 4; ++j) {
                    const float4 wa = *(const float4*)(wp + (u0 + j)*128);
                    const float4 wb = *(const float4*)(wp + (u0 + j)*128 + 4);
                    #pragma unroll
                    for (int k = 0; k < no; ++k) {
                        const float y = (j == 0) ? yv4[k].x
                                      : (j == 1) ? yv4[k].y
                                      : (j == 2) ? yv4[k].z
                                                 : yv4[k].w;
                        acc[0][ko+k] += wa.x * y;
                        acc[1][ko+k] += wa.y * y;
                        acc[2][ko+k] += wa.z * y;
                        acc[3][ko+k] += wa.w * y;
                        acc[4][ko+k] += wb.x * y;
                        acc[5][ko+k] += wb.y * y;
                        acc[6][ko+k] += wb.z * y;
                        acc[7][ko+k] += wb.w * y;
                    }
                }
            }
        }
        __syncthreads();
    }

    // Epilogue: out[b, so + w*(2lo+1) + k], w = tw*8 + c, all float4 stores
    {
        float* op = out + (b0 + cb)*1152;
        // io=0: 8 consecutive w at offset tw*8
        *(float4*)(op + tw*8)     = make_float4(acc[0][0], acc[1][0], acc[2][0], acc[3][0]);
        *(float4*)(op + tw*8 + 4) = make_float4(acc[4][0], acc[5][0], acc[6][0], acc[7][0]);
        // io=1: 24 consecutive floats at 128 + tw*24  (layout w*3+k)
        {
            float b1[24];
            #pragma unroll
            for (int c = 0; c < 8; ++c)
                #pragma unroll
                for (int k = 0; k < 3; ++k) b1[c*3 + k] = acc[c][1 + k];
            #pragma unroll
            for (int q = 0; q < 6; ++q)
                *(float4*)(op + 128 + tw*24 + q*4) = *(const float4*)(b1 + q*4);
        }
        // io=2: 40 consecutive floats at 512 + tw*40  (layout w*5+k)
        {
            float b2[40];
            #pragma unroll
            for (int c = 0; c < 8; ++c)
                #pragma unroll
                for (int k = 0; k < 5; ++k) b2[c*5 + k] = acc[c][4 + k];
            #pragma unroll
            for (int q = 0; q < 10; ++q)
                *(float4*)(op + 512 + tw*40 + q*4) = *(const float4*)(b2 + q*4);
        }
    }
}

// ---- launch ---------------------------------------------------------------
extern "C" void kernel_launch(void* const* d_in, const int* in_sizes, int n_in,
                              void* d_out, int out_size, void* d_ws, size_t ws_size,
                              hipStream_t stream) {
    const float* x1  = (const float*)d_in[0];
    const float* x2  = (const float*)d_in[1];
    const float* wsg = (const float*)d_in[2];
    float* out = (float*)d_out;
    const int B = in_sizes[0] / 1152;   // 32768

    TPConst tc;
    fill_const(tc);   // deterministic; identical on every call (graph-capture safe)

    dim3 grid(B / BT), block(256);
    hipLaunchKernelGGL(tp_kernel, grid, block, 0, stream, x1, x2, wsg, out, tc);
}